// Round 5
// baseline (653.954 us; speedup 1.0000x reference)
//
#include <hip/hip_runtime.h>
#include <hip/hip_bf16.h>

#define S_LEN 2048
#define BATCH 2
#define DMODEL 256
#define NHEAD 8
#define DKH 32
#define NTOK (S_LEN * BATCH)
#define OUT0_ELEMS ((size_t)NTOK * DMODEL)
#define SW (S_LEN / 32)  // mask words per row

typedef __bf16 bf16_t;
typedef __bf16 bf16x8 __attribute__((ext_vector_type(8)));
typedef __bf16 bf16x4 __attribute__((ext_vector_type(4)));
typedef float f32x4 __attribute__((ext_vector_type(4)));

#define MFMA16(a, b, c) __builtin_amdgcn_mfma_f32_16x16x32_bf16(a, b, c, 0, 0, 0)

// exp2: scores are pre-scaled by log2(e) in k_proj, so softmax is exact in
// exp2 domain and each exp is a single v_exp_f32.
#if defined(__has_builtin)
#if __has_builtin(__builtin_amdgcn_exp2f)
#define EXP2(x) __builtin_amdgcn_exp2f(x)
#endif
#endif
#ifndef EXP2
#define EXP2(x) __expf((x) * 0.6931471805599453f)
#endif

// -------- kernel 0: dtype probe (wave-parallel). flag=1 if fp32 -------------
__global__ void k_probe(const unsigned short* __restrict__ q, int* __restrict__ flag) {
  int lane = threadIdx.x & 63;
  int good = 0;
#pragma unroll
  for (int j = 0; j < 4; j++) {
    unsigned short u = q[(lane * 4 + j) * 2];
    int e = (u >> 7) & 0xFF;
    if ((u & 0x7FFF) == 0 || (e >= 110 && e <= 135)) good++;
  }
#pragma unroll
  for (int off = 1; off < 64; off <<= 1) good += __shfl_xor(good, off);
  if (threadIdx.x == 0) *flag = (good >= 200) ? 0 : 1;
}

// ---------------- kernel 1: fused prep --------------------------------------
// blocks [0,12288): convert q/k/v to bf16 (3 x 4096 blocks)
// blocks [12288,12544): transpose the 4 weight matrices
// blocks [12544,16640): transpose graph_pos [k][q][h] -> [h][q][k] + pack mask
// mode 0: gp -> bf16 gpt (workspace). mode 1: gp duplicated (flag dtype) into
// the attno region of d_out for b=0,1 (read-then-overwritten by k_attn).
__global__ __launch_bounds__(256) void k_prep(
    const void* __restrict__ qin, const void* __restrict__ kin,
    const void* __restrict__ vin, bf16_t* __restrict__ qc,
    bf16_t* __restrict__ kc, bf16_t* __restrict__ vc,
    const void* __restrict__ w_q, const void* __restrict__ w_k,
    const void* __restrict__ w_v, const void* __restrict__ w_fc,
    bf16_t* __restrict__ wt, const void* __restrict__ gp,
    bf16_t* __restrict__ gpt, void* __restrict__ attno_raw,
    const int* __restrict__ mask, unsigned int* __restrict__ mbits,
    const int* __restrict__ flag, int mode) {
  __shared__ __align__(16) char smem[32768];
  int bid = blockIdx.x, tid = threadIdx.x;
  int is32 = *flag;

  if (bid < 12288) {  // ---- convert q/k/v ----
    int which = bid >> 12;
    int i = (bid & 4095) * 256 + tid;
    const void* src = (which == 0) ? qin : (which == 1) ? kin : vin;
    bf16_t* dst = (which == 0) ? qc : (which == 1) ? kc : vc;
    if (i < NTOK * DMODEL)
      dst[i] = is32 ? (bf16_t)((const float*)src)[i] : ((const bf16_t*)src)[i];
    return;
  }

  if (bid < 12544) {  // ---- weight transpose ----
    auto tile = (bf16_t(*)[33])smem;
    int b2 = bid - 12288;
    int bz = b2 >> 6, bx = b2 & 7, by = (b2 >> 3) & 7;
    const void* w = (bz == 0) ? w_q : (bz == 1) ? w_k : (bz == 2) ? w_v : w_fc;
    bf16_t* o = wt + (size_t)bz * DMODEL * DMODEL;
    int tx = tid & 31, ty = tid >> 5;
    int x = bx * 32 + tx, y0 = by * 32;
    for (int j = ty; j < 32; j += 8) {
      size_t idx = (size_t)(y0 + j) * DMODEL + x;
      float v = is32 ? ((const float*)w)[idx] : (float)((const bf16_t*)w)[idx];
      tile[j][tx] = (bf16_t)v;
    }
    __syncthreads();
    for (int j = ty; j < 32; j += 8)
      o[(size_t)(bx * 32 + j) * DMODEL + y0 + tx] = tile[tx][j];
    return;
  }

  // ---- graph_pos transpose + mask bit-pack ----
  auto tile = (float(*)[8][32])smem;  // [k][h][q], 32 KB
  int b3 = bid - 12544;
  int bx = b3 & 63, by = b3 >> 6;
  int k0 = bx * 32, q0 = by * 32;
  int ci = tid & 63, krl = tid >> 6;
#pragma unroll
  for (int p = 0; p < 8; p++) {
    int kr = p * 4 + krl;
    size_t base = ((size_t)(k0 + kr) * S_LEN + q0) * NHEAD + ci * 4;
    f32x4 v;
    if (is32) {
      v = __builtin_nontemporal_load((const f32x4*)((const float*)gp + base));
    } else {
      bf16x4 bv = *(const bf16x4*)((const bf16_t*)gp + base);
      v[0] = (float)bv[0]; v[1] = (float)bv[1];
      v[2] = (float)bv[2]; v[3] = (float)bv[3];
    }
    int qq = ci >> 1, hb = (ci & 1) * 4;
    tile[kr][hb + 0][qq] = v[0];
    tile[kr][hb + 1][qq] = v[1];
    tile[kr][hb + 2][qq] = v[2];
    tile[kr][hb + 3][qq] = v[3];
  }
  __syncthreads();
  int h = tid >> 5, q = tid & 31;
  if (mode == 0) {
    bf16_t* orow = gpt + ((size_t)h * S_LEN + q0 + q) * S_LEN + k0;
#pragma unroll
    for (int j = 0; j < 4; j++) {
      bf16x8 o;
#pragma unroll
      for (int i2 = 0; i2 < 8; i2++) o[i2] = (bf16_t)tile[j * 8 + i2][h][q];
      *(bf16x8*)(orow + j * 8) = o;
    }
  } else {
    size_t ro = ((size_t)h * S_LEN + q0 + q) * S_LEN + k0;
    size_t bs = (size_t)NHEAD * S_LEN * S_LEN;
    if (is32) {
      float* o0 = (float*)attno_raw + OUT0_ELEMS + ro;
#pragma unroll
      for (int j = 0; j < 8; j++) {
        f32x4 o;
#pragma unroll
        for (int i2 = 0; i2 < 4; i2++) o[i2] = tile[j * 4 + i2][h][q];
        *(f32x4*)(o0 + j * 4) = o;
        *(f32x4*)(o0 + bs + j * 4) = o;
      }
    } else {
      bf16_t* o0 = (bf16_t*)attno_raw + OUT0_ELEMS + ro;
#pragma unroll
      for (int j = 0; j < 4; j++) {
        bf16x8 o;
#pragma unroll
        for (int i2 = 0; i2 < 8; i2++) o[i2] = (bf16_t)tile[j * 8 + i2][h][q];
        *(bf16x8*)(o0 + j * 8) = o;
        *(bf16x8*)(o0 + bs + j * 8) = o;
      }
    }
  }
  if (tid < 64) {
    int w = (by * 64 + bx) * 64 + tid;
    const int* src = mask + (size_t)w * 32;
    unsigned int bits = 0;
#pragma unroll
    for (int j = 0; j < 32; j += 4) {
      int4 m = *(const int4*)(src + j);
      if (m.x) bits |= 1u << j;
      if (m.y) bits |= 1u << (j + 1);
      if (m.z) bits |= 1u << (j + 2);
      if (m.w) bits |= 1u << (j + 3);
    }
    mbits[w] = bits;
  }
}

// ---------------- kernel 2: QKV projections via MFMA ------------------------
__global__ __launch_bounds__(256) void k_proj(
    const bf16_t* __restrict__ qin, const bf16_t* __restrict__ kin,
    const bf16_t* __restrict__ vin, const bf16_t* __restrict__ wt,
    bf16_t* __restrict__ qhi, bf16_t* __restrict__ qlo,
    bf16_t* __restrict__ khi, bf16_t* __restrict__ klo,
    bf16_t* __restrict__ vt) {
  int mat = blockIdx.z;
  const bf16_t* x = (mat == 0) ? qin : (mat == 1) ? kin : vin;
  const bf16_t* wm = wt + (size_t)mat * DMODEL * DMODEL;
  int t0 = blockIdx.x * 16;
  int lane = threadIdx.x & 63, wave = threadIdx.x >> 6;
  int col = lane & 15, quad = lane >> 4;
  f32x4 acc[4] = {};
  const bf16_t* xrow = x + (size_t)(t0 + col) * DMODEL + quad * 8;
  for (int kk = 0; kk < 8; kk++) {
    bf16x8 a = *(const bf16x8*)(xrow + kk * 32);
#pragma unroll
    for (int nt = 0; nt < 4; nt++) {
      int n0 = wave * 64 + nt * 16;
      bf16x8 bw = *(const bf16x8*)(wm + (size_t)(n0 + col) * DMODEL + kk * 32 + quad * 8);
      acc[nt] = MFMA16(a, bw, acc[nt]);
    }
  }
  // 1/sqrt(32) * log2(e): softmax computed in exp2 domain in k_attn
  const float qscale = 0.2550348612f;
#pragma unroll
  for (int nt = 0; nt < 4; nt++) {
    int n = wave * 64 + nt * 16 + col;
    int h = n >> 5, dk = n & 31;
#pragma unroll
    for (int r = 0; r < 4; r++) {
      int t = t0 + quad * 4 + r;
      int s = t >> 1, bb = t & 1;
      float val = acc[nt][r];
      if (mat == 0) val *= qscale;
      if (mat <= 1) {
        bf16_t hi = (bf16_t)val;
        bf16_t lo = (bf16_t)(val - (float)hi);
        size_t idx = ((size_t)(bb * NHEAD + h) * S_LEN + s) * DKH + dk;
        if (mat == 0) { qhi[idx] = hi; qlo[idx] = lo; }
        else         { khi[idx] = hi; klo[idx] = lo; }
      } else {
        vt[((size_t)(bb * NHEAD + h) * DKH + dk) * S_LEN + s] = (bf16_t)val;
      }
    }
  }
}

// ---------------- kernel 3: attention ---------------------------------------
// Grid (128,2,8): x=q0 (fastest -> round-robins across XCDs within one head),
// y=b, z=h. The two readers of each bias line, blocks (h,0,q0) and (h,1,q0),
// are 128 linear IDs apart: same XCD (128%8==0) and temporally adjacent, so
// the second bias read is an L2 hit. Heads stream sequentially -> small L2/L3
// working set. (R3/R4's XCD-private-head swizzle ran 16 disjoint streams
// concurrently and nearly doubled HBM traffic: 351 -> 620 MB.)
// Softmax uses a FIXED shift of 0: scores are ~N(0,1.4^2) in exp2 domain
// (max over 2048 keys ~ 8, comfortably in fp32), masked lanes hit
// exp2(-1e9) = 0, and softmax is shift-invariant -> no max tracking, no
// serial max/l dependency chain in pass 1.
// attno is stored directly from the computing lane; the 4 tt-subtiles are
// buffered in regs and stored back-to-back so each row gets 256B contiguous.
template <int BMODE>
__global__ __launch_bounds__(256, 8) void k_attn(
    const bf16_t* __restrict__ qhi, const bf16_t* __restrict__ qlo,
    const bf16_t* __restrict__ khi, const bf16_t* __restrict__ klo,
    const bf16_t* __restrict__ vtg, const bf16_t* __restrict__ gpt,
    const unsigned int* __restrict__ mbits, void* __restrict__ attno_raw,
    float* __restrict__ attn_out, const int* __restrict__ flag) {
  __shared__ __align__(16) bf16_t lds_pb[4][16][72];  // P*bias; reused for O-combine
  __shared__ float lds_l[4][16];

  int is32 = *flag;
  float*  attno_f = (float*)attno_raw + OUT0_ELEMS;
  bf16_t* attno_b = (bf16_t*)attno_raw + OUT0_ELEMS;

  int q0 = blockIdx.x * 16;
  int b = blockIdx.y, h = blockIdx.z;

  int lane = threadIdx.x & 63, wave = threadIdx.x >> 6;
  int col = lane & 15, quad = lane >> 4;
  int kbase = wave * 512;
  size_t head = (size_t)(b * NHEAD + h);
  const bf16_t* Qh = qhi + head * S_LEN * DKH;
  const bf16_t* Ql = qlo + head * S_LEN * DKH;
  const bf16_t* Kh = khi + head * S_LEN * DKH;
  const bf16_t* Kl = klo + head * S_LEN * DKH;
  const bf16_t* Vt = vtg + head * DKH * S_LEN;
  const unsigned int* mrow =
      mbits + ((size_t)b * S_LEN + q0 + col) * SW + (kbase >> 5);
  const bf16_t* gprow = gpt + ((size_t)h * S_LEN + q0 + col) * S_LEN + kbase;
  size_t brow = head * S_LEN * S_LEN + (size_t)(q0 + col) * S_LEN + kbase;

  bf16x8 qhF = *(const bf16x8*)(Qh + (q0 + col) * DKH + quad * 8);
  bf16x8 qlF = *(const bf16x8*)(Ql + (q0 + col) * DKH + quad * 8);

  // ---- pass 1: l = sum exp2(s) over this wave's 512 keys (fixed shift) ----
  // 4 independent vector accumulators: no serial dependency chain.
  f32x4 lacc = {};
#pragma unroll
  for (int t = 0; t < 32; t++) {
    int k0 = kbase + t * 16;
    bf16x8 khF = *(const bf16x8*)(Kh + (size_t)(k0 + col) * DKH + quad * 8);
    bf16x8 klF = *(const bf16x8*)(Kl + (size_t)(k0 + col) * DKH + quad * 8);
    f32x4 sc = {};
    sc = MFMA16(khF, qhF, sc);
    sc = MFMA16(khF, qlF, sc);
    sc = MFMA16(klF, qhF, sc);
    unsigned int mw = mrow[t >> 1];
    int mb = (int)(mw >> ((t & 1) * 16 + quad * 4)) & 0xF;
#pragma unroll
    for (int r = 0; r < 4; r++) {
      float sv = (mb & (1 << r)) ? sc[r] : -1e9f;
      lacc[r] += EXP2(sv);
    }
  }
  float l = (lacc[0] + lacc[1]) + (lacc[2] + lacc[3]);
  l += __shfl_xor(l, 16);
  l += __shfl_xor(l, 32);
  if (lane < 16) lds_l[wave][lane] = l;
  __syncthreads();
  l = (lds_l[0][col] + lds_l[1][col]) + (lds_l[2][col] + lds_l[3][col]);
  float invl = 1.0f / l;

  // ---- pass 2: recompute, emit attno (grouped stores), accumulate PV ----
  f32x4 oacc[2] = {};
  for (int c = 0; c < 8; c++) {
    f32x4 ps[4];
#pragma unroll
    for (int tt = 0; tt < 4; tt++) {
      int k0 = kbase + c * 64 + tt * 16;
      bf16x8 khF = *(const bf16x8*)(Kh + (size_t)(k0 + col) * DKH + quad * 8);
      bf16x8 klF = *(const bf16x8*)(Kl + (size_t)(k0 + col) * DKH + quad * 8);
      f32x4 sc = {};
      sc = MFMA16(khF, qhF, sc);
      sc = MFMA16(khF, qlF, sc);
      sc = MFMA16(klF, qhF, sc);
      unsigned int mw = mrow[c * 2 + (tt >> 1)];
      int mb = (int)(mw >> ((tt & 1) * 16 + quad * 4)) & 0xF;
      float bias[4];
      if (BMODE == 0) {
        bf16x4 b4 = *(const bf16x4*)(gprow + c * 64 + tt * 16 + quad * 4);
#pragma unroll
        for (int r = 0; r < 4; r++) bias[r] = (float)b4[r];
      } else {
        if (is32) {
          f32x4 b4 = *(const f32x4*)(attno_f + brow + c * 64 + tt * 16 + quad * 4);
#pragma unroll
          for (int r = 0; r < 4; r++) bias[r] = b4[r];
        } else {
          bf16x4 b4 = *(const bf16x4*)(attno_b + brow + c * 64 + tt * 16 + quad * 4);
#pragma unroll
          for (int r = 0; r < 4; r++) bias[r] = (float)b4[r];
        }
      }
      bf16x4 pbv;
#pragma unroll
      for (int r = 0; r < 4; r++) {
        float sv = (mb & (1 << r)) ? sc[r] : -1e9f;
        float pp = EXP2(sv) * invl;
        ps[tt][r] = pp;
        pbv[r] = (bf16_t)(pp * bias[r]);
      }
      *(bf16x4*)&lds_pb[wave][col][tt * 16 + quad * 4] = pbv;
    }
    {  // grouped attno stores: 4 back-to-back -> 256B contiguous per row
      size_t sa0 = brow + c * 64 + quad * 4;
      if (is32) {
#pragma unroll
        for (int tt = 0; tt < 4; tt++)
          *(f32x4*)(attno_f + sa0 + tt * 16) = ps[tt];
      } else {
#pragma unroll
        for (int tt = 0; tt < 4; tt++) {
          bf16x4 pv;
#pragma unroll
          for (int r = 0; r < 4; r++) pv[r] = (bf16_t)ps[tt][r];
          *(bf16x4*)(attno_b + sa0 + tt * 16) = pv;
        }
      }
    }
#pragma unroll
    for (int ks = 0; ks < 2; ks++) {
      bf16x8 pf = *(const bf16x8*)&lds_pb[wave][col][ks * 32 + quad * 8];
#pragma unroll
      for (int dt = 0; dt < 2; dt++) {
        bf16x8 vf = *(const bf16x8*)(Vt + (size_t)(dt * 16 + col) * S_LEN + kbase + c * 64 + ks * 32 + quad * 8);
        oacc[dt] = MFMA16(vf, pf, oacc[dt]);
      }
    }
  }
  // combine O across waves; reuse lds_pb (dead after PV) as float[16][34]/wave
  {
    float* lo = (float*)&lds_pb[wave][0][0];
#pragma unroll
    for (int dt = 0; dt < 2; dt++)
#pragma unroll
      for (int r = 0; r < 4; r++)
        lo[col * 34 + dt * 16 + quad * 4 + r] = oacc[dt][r];
  }
  __syncthreads();
  if (wave == 0) {
    int t = (q0 + col) * BATCH + b;
#pragma unroll
    for (int dt = 0; dt < 2; dt++) {
      f32x4 vv = {};
#pragma unroll
      for (int w = 0; w < 4; w++) {
        const float* lw = (const float*)&lds_pb[w][0][0];
#pragma unroll
        for (int r2 = 0; r2 < 4; r2++)
          vv[r2] += lw[col * 34 + dt * 16 + quad * 4 + r2];
      }
      *(f32x4*)(attn_out + (size_t)t * DMODEL + h * DKH + dt * 16 + quad * 4) = vv;
    }
  }
}

// ---------------- kernel 4: FC + residual + LayerNorm -----------------------
__global__ __launch_bounds__(256) void k_fc_ln(
    const float* __restrict__ attn_out, const bf16_t* __restrict__ wtfc,
    const bf16_t* __restrict__ qc, const void* __restrict__ gamma,
    const void* __restrict__ beta, void* __restrict__ out0,
    const int* __restrict__ flag) {
  __shared__ float lds_sx[4][16];
  __shared__ float lds_sq[4][16];
  int is32 = *flag;
  int t0 = blockIdx.x * 16;
  int lane = threadIdx.x & 63, wave = threadIdx.x >> 6;
  int col = lane & 15, quad = lane >> 4;
  f32x4 acc[4] = {};
  const float* arow = attn_out + (size_t)(t0 + col) * DMODEL + quad * 8;
  for (int kk = 0; kk < 8; kk++) {
    float4 a0 = *(const float4*)(arow + kk * 32);
    float4 a1 = *(const float4*)(arow + kk * 32 + 4);
    float av[8] = {a0.x, a0.y, a0.z, a0.w, a1.x, a1.y, a1.z, a1.w};
    bf16x8 ahi, alo;
#pragma unroll
    for (int j = 0; j < 8; j++) {
      bf16_t hi = (bf16_t)av[j];
      ahi[j] = hi;
      alo[j] = (bf16_t)(av[j] - (float)hi);
    }
#pragma unroll
    for (int nt = 0; nt < 4; nt++) {
      int n0 = wave * 64 + nt * 16;
      bf16x8 bfr = *(const bf16x8*)(wtfc + (size_t)(n0 + col) * DMODEL + kk * 32 + quad * 8);
      acc[nt] = MFMA16(ahi, bfr, acc[nt]);
      acc[nt] = MFMA16(alo, bfr, acc[nt]);
    }
  }
#pragma unroll
  for (int nt = 0; nt < 4; nt++) {
    int n = wave * 64 + nt * 16 + col;
#pragma unroll
    for (int r = 0; r < 4; r++) {
      int t = t0 + quad * 4 + r;
      acc[nt][r] += (float)qc[(size_t)t * DMODEL + n];
    }
  }
  float sx[4], sq[4];
#pragma unroll
  for (int r = 0; r < 4; r++) {
    float s = 0, s2 = 0;
#pragma unroll
    for (int nt = 0; nt < 4; nt++) { float v = acc[nt][r]; s += v; s2 += v * v; }
    sx[r] = s; sq[r] = s2;
  }
#pragma unroll
  for (int off = 1; off < 16; off <<= 1) {
#pragma unroll
    for (int r = 0; r < 4; r++) {
      sx[r] += __shfl_xor(sx[r], off);
      sq[r] += __shfl_xor(sq[r], off);
    }
  }
  if (col == 0) {
#pragma unroll
    for (int r = 0; r < 4; r++) {
      lds_sx[wave][quad * 4 + r] = sx[r];
      lds_sq[wave][quad * 4 + r] = sq[r];
    }
  }
  __syncthreads();
#pragma unroll
  for (int r = 0; r < 4; r++) {
    int tl = quad * 4 + r;
    float tsx = lds_sx[0][tl] + lds_sx[1][tl] + lds_sx[2][tl] + lds_sx[3][tl];
    float tsq = lds_sq[0][tl] + lds_sq[1][tl] + lds_sq[2][tl] + lds_sq[3][tl];
    float mu = tsx * (1.0f / 256.0f);
    float var = tsq * (1.0f / 256.0f) - mu * mu;
    float rs = rsqrtf(var + 1e-6f);
    int t = t0 + tl;
#pragma unroll
    for (int nt = 0; nt < 4; nt++) {
      int n = wave * 64 + nt * 16 + col;
      float g = is32 ? ((const float*)gamma)[n] : (float)((const bf16_t*)gamma)[n];
      float bt = is32 ? ((const float*)beta)[n] : (float)((const bf16_t*)beta)[n];
      float val = (acc[nt][r] - mu) * rs * g + bt;
      if (is32) ((float*)out0)[(size_t)t * DMODEL + n] = val;
      else      ((bf16_t*)out0)[(size_t)t * DMODEL + n] = (bf16_t)val;
    }
  }
}

extern "C" void kernel_launch(void* const* d_in, const int* in_sizes, int n_in,
                              void* d_out, int out_size, void* d_ws, size_t ws_size,
                              hipStream_t stream) {
  (void)in_sizes; (void)n_in; (void)out_size;
  const void* qin   = d_in[0];
  const void* kin   = d_in[1];
  const void* vin   = d_in[2];
  const void* gp    = d_in[3];
  const int*  mask  = (const int*)d_in[4];
  const void* w_q   = d_in[5];
  const void* w_k   = d_in[6];
  const void* w_v   = d_in[7];
  const void* w_fc  = d_in[8];
  const void* gamma = d_in[9];
  const void* beta  = d_in[10];

  char* ws = (char*)d_ws;
  bf16_t* wt  = (bf16_t*)(ws);                  // 512 KB
  int* flag = (int*)(ws + (1u << 19));          // 4 B (after wt)
  bf16_t* qc  = (bf16_t*)(ws + (1u << 20));     // 2 MB
  bf16_t* kc  = (bf16_t*)(ws + (3u << 20));     // 2 MB
  bf16_t* vc  = (bf16_t*)(ws + (5u << 20));     // 2 MB
  bf16_t* qhi = (bf16_t*)(ws + (7u << 20));
  bf16_t* qlo = (bf16_t*)(ws + (9u << 20));
  bf16_t* khi = (bf16_t*)(ws + (11u << 20));
  bf16_t* klo = (bf16_t*)(ws + (13u << 20));
  bf16_t* vt  = (bf16_t*)(ws + (15u << 20));
  float* attn_out = (float*)(ws + (17u << 20)); // 4 MB
  unsigned int* mbits = (unsigned int*)(ws + (21u << 20));  // 1 MB
  bf16_t* gpt = (bf16_t*)(ws + (22u << 20));    // 64 MB when available

  bool use_ws_gpt = ws_size >= (((size_t)86 << 20) + 64);

  hipLaunchKernelGGL(k_probe, dim3(1), dim3(64), 0, stream,
                     (const unsigned short*)qin, flag);
  hipLaunchKernelGGL(k_prep, dim3(16640), dim3(256), 0, stream,
                     qin, kin, vin, qc, kc, vc, w_q, w_k, w_v, w_fc, wt,
                     gp, gpt, d_out, mask, mbits, flag, use_ws_gpt ? 0 : 1);
  hipLaunchKernelGGL(k_proj, dim3(256, 1, 3), dim3(256), 0, stream,
                     qc, kc, vc, wt, qhi, qlo, khi, klo, vt);
  if (use_ws_gpt) {
    hipLaunchKernelGGL((k_attn<0>), dim3(128, 2, 8), dim3(256), 0, stream,
                       qhi, qlo, khi, klo, vt, gpt, mbits, d_out, attn_out, flag);
  } else {
    hipLaunchKernelGGL((k_attn<1>), dim3(128, 2, 8), dim3(256), 0, stream,
                       qhi, qlo, khi, klo, vt, gpt, mbits, d_out, attn_out, flag);
  }
  hipLaunchKernelGGL(k_fc_ln, dim3(256), dim3(256), 0, stream,
                     attn_out, wt + 3 * DMODEL * DMODEL, qc, gamma, beta, d_out, flag);
}

// Round 6
// 571.886 us; speedup vs baseline: 1.1435x; 1.1435x over previous
//
#include <hip/hip_runtime.h>
#include <hip/hip_bf16.h>

#define S_LEN 2048
#define BATCH 2
#define DMODEL 256
#define NHEAD 8
#define DKH 32
#define NTOK (S_LEN * BATCH)
#define OUT0_ELEMS ((size_t)NTOK * DMODEL)
#define SW (S_LEN / 32)  // mask words per row

typedef __bf16 bf16_t;
typedef __bf16 bf16x8 __attribute__((ext_vector_type(8)));
typedef __bf16 bf16x4 __attribute__((ext_vector_type(4)));
typedef float f32x4 __attribute__((ext_vector_type(4)));

#define MFMA16(a, b, c) __builtin_amdgcn_mfma_f32_16x16x32_bf16(a, b, c, 0, 0, 0)

// exp2: scores are pre-scaled by log2(e) in k_proj, so softmax is exact in
// exp2 domain and each exp is a single v_exp_f32.
#if defined(__has_builtin)
#if __has_builtin(__builtin_amdgcn_exp2f)
#define EXP2(x) __builtin_amdgcn_exp2f(x)
#endif
#endif
#ifndef EXP2
#define EXP2(x) __expf((x) * 0.6931471805599453f)
#endif

// -------- kernel 0: dtype probe (wave-parallel). flag=1 if fp32 -------------
__global__ void k_probe(const unsigned short* __restrict__ q, int* __restrict__ flag) {
  int lane = threadIdx.x & 63;
  int good = 0;
#pragma unroll
  for (int j = 0; j < 4; j++) {
    unsigned short u = q[(lane * 4 + j) * 2];
    int e = (u >> 7) & 0xFF;
    if ((u & 0x7FFF) == 0 || (e >= 110 && e <= 135)) good++;
  }
#pragma unroll
  for (int off = 1; off < 64; off <<= 1) good += __shfl_xor(good, off);
  if (threadIdx.x == 0) *flag = (good >= 200) ? 0 : 1;
}

// ---------------- kernel 1: fused prep --------------------------------------
// blocks [0,12288): convert q/k/v to bf16 (3 x 4096 blocks)
// blocks [12288,12544): transpose the 4 weight matrices
// blocks [12544,16640): transpose graph_pos [k][q][h] -> [h][q][k] + pack mask
// mode 0: gp -> bf16 gpt (workspace). mode 1: gp duplicated (flag dtype) into
// the attno region of d_out for b=0,1 (read-then-overwritten by k_attn).
__global__ __launch_bounds__(256) void k_prep(
    const void* __restrict__ qin, const void* __restrict__ kin,
    const void* __restrict__ vin, bf16_t* __restrict__ qc,
    bf16_t* __restrict__ kc, bf16_t* __restrict__ vc,
    const void* __restrict__ w_q, const void* __restrict__ w_k,
    const void* __restrict__ w_v, const void* __restrict__ w_fc,
    bf16_t* __restrict__ wt, const void* __restrict__ gp,
    bf16_t* __restrict__ gpt, void* __restrict__ attno_raw,
    const int* __restrict__ mask, unsigned int* __restrict__ mbits,
    const int* __restrict__ flag, int mode) {
  __shared__ __align__(16) char smem[32768];
  int bid = blockIdx.x, tid = threadIdx.x;
  int is32 = *flag;

  if (bid < 12288) {  // ---- convert q/k/v ----
    int which = bid >> 12;
    int i = (bid & 4095) * 256 + tid;
    const void* src = (which == 0) ? qin : (which == 1) ? kin : vin;
    bf16_t* dst = (which == 0) ? qc : (which == 1) ? kc : vc;
    if (i < NTOK * DMODEL)
      dst[i] = is32 ? (bf16_t)((const float*)src)[i] : ((const bf16_t*)src)[i];
    return;
  }

  if (bid < 12544) {  // ---- weight transpose ----
    auto tile = (bf16_t(*)[33])smem;
    int b2 = bid - 12288;
    int bz = b2 >> 6, bx = b2 & 7, by = (b2 >> 3) & 7;
    const void* w = (bz == 0) ? w_q : (bz == 1) ? w_k : (bz == 2) ? w_v : w_fc;
    bf16_t* o = wt + (size_t)bz * DMODEL * DMODEL;
    int tx = tid & 31, ty = tid >> 5;
    int x = bx * 32 + tx, y0 = by * 32;
    for (int j = ty; j < 32; j += 8) {
      size_t idx = (size_t)(y0 + j) * DMODEL + x;
      float v = is32 ? ((const float*)w)[idx] : (float)((const bf16_t*)w)[idx];
      tile[j][tx] = (bf16_t)v;
    }
    __syncthreads();
    for (int j = ty; j < 32; j += 8)
      o[(size_t)(bx * 32 + j) * DMODEL + y0 + tx] = tile[tx][j];
    return;
  }

  // ---- graph_pos transpose + mask bit-pack ----
  auto tile = (float(*)[8][32])smem;  // [k][h][q], 32 KB
  int b3 = bid - 12544;
  int bx = b3 & 63, by = b3 >> 6;
  int k0 = bx * 32, q0 = by * 32;
  int ci = tid & 63, krl = tid >> 6;
#pragma unroll
  for (int p = 0; p < 8; p++) {
    int kr = p * 4 + krl;
    size_t base = ((size_t)(k0 + kr) * S_LEN + q0) * NHEAD + ci * 4;
    f32x4 v;
    if (is32) {
      v = __builtin_nontemporal_load((const f32x4*)((const float*)gp + base));
    } else {
      bf16x4 bv = *(const bf16x4*)((const bf16_t*)gp + base);
      v[0] = (float)bv[0]; v[1] = (float)bv[1];
      v[2] = (float)bv[2]; v[3] = (float)bv[3];
    }
    int qq = ci >> 1, hb = (ci & 1) * 4;
    tile[kr][hb + 0][qq] = v[0];
    tile[kr][hb + 1][qq] = v[1];
    tile[kr][hb + 2][qq] = v[2];
    tile[kr][hb + 3][qq] = v[3];
  }
  __syncthreads();
  int h = tid >> 5, q = tid & 31;
  if (mode == 0) {
    bf16_t* orow = gpt + ((size_t)h * S_LEN + q0 + q) * S_LEN + k0;
#pragma unroll
    for (int j = 0; j < 4; j++) {
      bf16x8 o;
#pragma unroll
      for (int i2 = 0; i2 < 8; i2++) o[i2] = (bf16_t)tile[j * 8 + i2][h][q];
      *(bf16x8*)(orow + j * 8) = o;
    }
  } else {
    size_t ro = ((size_t)h * S_LEN + q0 + q) * S_LEN + k0;
    size_t bs = (size_t)NHEAD * S_LEN * S_LEN;
    if (is32) {
      float* o0 = (float*)attno_raw + OUT0_ELEMS + ro;
#pragma unroll
      for (int j = 0; j < 8; j++) {
        f32x4 o;
#pragma unroll
        for (int i2 = 0; i2 < 4; i2++) o[i2] = tile[j * 4 + i2][h][q];
        *(f32x4*)(o0 + j * 4) = o;
        *(f32x4*)(o0 + bs + j * 4) = o;
      }
    } else {
      bf16_t* o0 = (bf16_t*)attno_raw + OUT0_ELEMS + ro;
#pragma unroll
      for (int j = 0; j < 4; j++) {
        bf16x8 o;
#pragma unroll
        for (int i2 = 0; i2 < 8; i2++) o[i2] = (bf16_t)tile[j * 8 + i2][h][q];
        *(bf16x8*)(o0 + j * 8) = o;
        *(bf16x8*)(o0 + bs + j * 8) = o;
      }
    }
  }
  if (tid < 64) {
    int w = (by * 64 + bx) * 64 + tid;
    const int* src = mask + (size_t)w * 32;
    unsigned int bits = 0;
#pragma unroll
    for (int j = 0; j < 32; j += 4) {
      int4 m = *(const int4*)(src + j);
      if (m.x) bits |= 1u << j;
      if (m.y) bits |= 1u << (j + 1);
      if (m.z) bits |= 1u << (j + 2);
      if (m.w) bits |= 1u << (j + 3);
    }
    mbits[w] = bits;
  }
}

// ---------------- kernel 2: QKV projections via MFMA ------------------------
__global__ __launch_bounds__(256) void k_proj(
    const bf16_t* __restrict__ qin, const bf16_t* __restrict__ kin,
    const bf16_t* __restrict__ vin, const bf16_t* __restrict__ wt,
    bf16_t* __restrict__ qhi, bf16_t* __restrict__ qlo,
    bf16_t* __restrict__ khi, bf16_t* __restrict__ klo,
    bf16_t* __restrict__ vt) {
  int mat = blockIdx.z;
  const bf16_t* x = (mat == 0) ? qin : (mat == 1) ? kin : vin;
  const bf16_t* wm = wt + (size_t)mat * DMODEL * DMODEL;
  int t0 = blockIdx.x * 16;
  int lane = threadIdx.x & 63, wave = threadIdx.x >> 6;
  int col = lane & 15, quad = lane >> 4;
  f32x4 acc[4] = {};
  const bf16_t* xrow = x + (size_t)(t0 + col) * DMODEL + quad * 8;
  for (int kk = 0; kk < 8; kk++) {
    bf16x8 a = *(const bf16x8*)(xrow + kk * 32);
#pragma unroll
    for (int nt = 0; nt < 4; nt++) {
      int n0 = wave * 64 + nt * 16;
      bf16x8 bw = *(const bf16x8*)(wm + (size_t)(n0 + col) * DMODEL + kk * 32 + quad * 8);
      acc[nt] = MFMA16(a, bw, acc[nt]);
    }
  }
  // 1/sqrt(32) * log2(e): softmax computed in exp2 domain in k_attn
  const float qscale = 0.2550348612f;
#pragma unroll
  for (int nt = 0; nt < 4; nt++) {
    int n = wave * 64 + nt * 16 + col;
    int h = n >> 5, dk = n & 31;
#pragma unroll
    for (int r = 0; r < 4; r++) {
      int t = t0 + quad * 4 + r;
      int s = t >> 1, bb = t & 1;
      float val = acc[nt][r];
      if (mat == 0) val *= qscale;
      if (mat <= 1) {
        bf16_t hi = (bf16_t)val;
        bf16_t lo = (bf16_t)(val - (float)hi);
        size_t idx = ((size_t)(bb * NHEAD + h) * S_LEN + s) * DKH + dk;
        if (mat == 0) { qhi[idx] = hi; qlo[idx] = lo; }
        else         { khi[idx] = hi; klo[idx] = lo; }
      } else {
        vt[((size_t)(bb * NHEAD + h) * DKH + dk) * S_LEN + s] = (bf16_t)val;
      }
    }
  }
}

// ---------------- kernel 3: attention ---------------------------------------
// Grid (128,8,2) (x=q0, y=h, z=b) -- the R2 configuration that measured
// FETCH 84 MB / WRITE 267 MB. Occupancy capped at 5 blocks/CU (R2 regime):
// R4/R5 showed that 8 blocks/CU + partial-line attno stores causes
// read-modify-write thrash (+115 MB on BOTH fetch and write).
// Softmax uses a FIXED shift of 0 (exp2 domain, fp32-safe, shift-invariant).
// attno store path: normalized P is staged in LDS per c-step, then stored
// with a lane remap (lane = row*8+seg, rows 8 per instruction x 128 B
// contiguous) so EVERY store instruction writes complete 128 B lines --
// line completion no longer depends on L2 retention or concurrency.
template <int BMODE>
__global__ __launch_bounds__(256, 5) void k_attn(
    const bf16_t* __restrict__ qhi, const bf16_t* __restrict__ qlo,
    const bf16_t* __restrict__ khi, const bf16_t* __restrict__ klo,
    const bf16_t* __restrict__ vtg, const bf16_t* __restrict__ gpt,
    const unsigned int* __restrict__ mbits, void* __restrict__ attno_raw,
    float* __restrict__ attn_out, const int* __restrict__ flag) {
  __shared__ __align__(16) float lds_pn[4][16][68];   // normalized P; reused for O-combine
  __shared__ __align__(16) bf16_t lds_pb[4][16][72];  // P*bias fragments for PV
  __shared__ float lds_l[4][16];

  int is32 = *flag;
  float*  attno_f = (float*)attno_raw + OUT0_ELEMS;
  bf16_t* attno_b = (bf16_t*)attno_raw + OUT0_ELEMS;

  int q0 = blockIdx.x * 16;
  int h = blockIdx.y, b = blockIdx.z;

  int lane = threadIdx.x & 63, wave = threadIdx.x >> 6;
  int col = lane & 15, quad = lane >> 4;
  int srow = lane >> 3, seg = lane & 7;  // attno-store lane remap
  int kbase = wave * 512;
  size_t head = (size_t)(b * NHEAD + h);
  const bf16_t* Qh = qhi + head * S_LEN * DKH;
  const bf16_t* Ql = qlo + head * S_LEN * DKH;
  const bf16_t* Kh = khi + head * S_LEN * DKH;
  const bf16_t* Kl = klo + head * S_LEN * DKH;
  const bf16_t* Vt = vtg + head * DKH * S_LEN;
  const unsigned int* mrow =
      mbits + ((size_t)b * S_LEN + q0 + col) * SW + (kbase >> 5);
  const bf16_t* gprow = gpt + ((size_t)h * S_LEN + q0 + col) * S_LEN + kbase;
  size_t brow = head * S_LEN * S_LEN + (size_t)(q0 + col) * S_LEN + kbase;

  bf16x8 qhF = *(const bf16x8*)(Qh + (q0 + col) * DKH + quad * 8);
  bf16x8 qlF = *(const bf16x8*)(Ql + (q0 + col) * DKH + quad * 8);

  // ---- pass 1: l = sum exp2(s) over this wave's 512 keys (fixed shift) ----
  f32x4 lacc = {};
#pragma unroll
  for (int t = 0; t < 32; t++) {
    int k0 = kbase + t * 16;
    bf16x8 khF = *(const bf16x8*)(Kh + (size_t)(k0 + col) * DKH + quad * 8);
    bf16x8 klF = *(const bf16x8*)(Kl + (size_t)(k0 + col) * DKH + quad * 8);
    f32x4 sc = {};
    sc = MFMA16(khF, qhF, sc);
    sc = MFMA16(khF, qlF, sc);
    sc = MFMA16(klF, qhF, sc);
    unsigned int mw = mrow[t >> 1];
    int mb = (int)(mw >> ((t & 1) * 16 + quad * 4)) & 0xF;
#pragma unroll
    for (int r = 0; r < 4; r++) {
      float sv = (mb & (1 << r)) ? sc[r] : -1e9f;
      lacc[r] += EXP2(sv);
    }
  }
  float l = (lacc[0] + lacc[1]) + (lacc[2] + lacc[3]);
  l += __shfl_xor(l, 16);
  l += __shfl_xor(l, 32);
  if (lane < 16) lds_l[wave][lane] = l;
  __syncthreads();
  l = (lds_l[0][col] + lds_l[1][col]) + (lds_l[2][col] + lds_l[3][col]);
  float invl = 1.0f / l;

  // ---- pass 2: recompute, stage P in LDS, full-line attno stores, PV ----
  f32x4 oacc[2] = {};
  for (int c = 0; c < 8; c++) {
#pragma unroll
    for (int tt = 0; tt < 4; tt++) {
      int k0 = kbase + c * 64 + tt * 16;
      bf16x8 khF = *(const bf16x8*)(Kh + (size_t)(k0 + col) * DKH + quad * 8);
      bf16x8 klF = *(const bf16x8*)(Kl + (size_t)(k0 + col) * DKH + quad * 8);
      f32x4 sc = {};
      sc = MFMA16(khF, qhF, sc);
      sc = MFMA16(khF, qlF, sc);
      sc = MFMA16(klF, qhF, sc);
      unsigned int mw = mrow[c * 2 + (tt >> 1)];
      int mb = (int)(mw >> ((tt & 1) * 16 + quad * 4)) & 0xF;
      float bias[4];
      if (BMODE == 0) {
        bf16x4 b4 = *(const bf16x4*)(gprow + c * 64 + tt * 16 + quad * 4);
#pragma unroll
        for (int r = 0; r < 4; r++) bias[r] = (float)b4[r];
      } else {
        if (is32) {
          f32x4 b4 = *(const f32x4*)(attno_f + brow + c * 64 + tt * 16 + quad * 4);
#pragma unroll
          for (int r = 0; r < 4; r++) bias[r] = b4[r];
        } else {
          bf16x4 b4 = *(const bf16x4*)(attno_b + brow + c * 64 + tt * 16 + quad * 4);
#pragma unroll
          for (int r = 0; r < 4; r++) bias[r] = (float)b4[r];
        }
      }
      f32x4 pf32;
      bf16x4 pbv;
#pragma unroll
      for (int r = 0; r < 4; r++) {
        float sv = (mb & (1 << r)) ? sc[r] : -1e9f;
        float pp = EXP2(sv) * invl;
        pf32[r] = pp;
        pbv[r] = (bf16_t)(pp * bias[r]);
      }
      *(f32x4*)&lds_pn[wave][col][tt * 16 + quad * 4] = pf32;
      *(bf16x4*)&lds_pb[wave][col][tt * 16 + quad * 4] = pbv;
    }
    // ---- attno store, full 128B lines per instruction ----
    // lane (srow, seg): rows srow and srow+8; per instruction the wave
    // covers 8 rows x 128 B contiguous = 8 complete lines.
    if (is32) {
#pragma unroll
      for (int half = 0; half < 2; half++) {
        int row = srow + (half << 3);
        float* ga = attno_f + head * S_LEN * S_LEN +
                    (size_t)(q0 + row) * S_LEN + kbase + c * 64;
#pragma unroll
        for (int part = 0; part < 2; part++) {
          f32x4 v = *(const f32x4*)&lds_pn[wave][row][part * 32 + seg * 4];
          *(f32x4*)(ga + part * 32 + seg * 4) = v;
        }
      }
    } else {
#pragma unroll
      for (int half = 0; half < 2; half++) {
        int row = srow + (half << 3);
        bf16_t* ga = attno_b + head * S_LEN * S_LEN +
                     (size_t)(q0 + row) * S_LEN + kbase + c * 64;
        bf16x8 ov;
#pragma unroll
        for (int jj = 0; jj < 8; jj++)
          ov[jj] = (bf16_t)lds_pn[wave][row][seg * 8 + jj];
        *(bf16x8*)(ga + seg * 8) = ov;
      }
    }
#pragma unroll
    for (int ks = 0; ks < 2; ks++) {
      bf16x8 pf = *(const bf16x8*)&lds_pb[wave][col][ks * 32 + quad * 8];
#pragma unroll
      for (int dt = 0; dt < 2; dt++) {
        bf16x8 vf = *(const bf16x8*)(Vt + (size_t)(dt * 16 + col) * S_LEN + kbase + c * 64 + ks * 32 + quad * 8);
        oacc[dt] = MFMA16(vf, pf, oacc[dt]);
      }
    }
  }
  // combine O across waves; reuse lds_pn (dead after stores) as [16][34]/wave
  {
    float* lo = &lds_pn[wave][0][0];
#pragma unroll
    for (int dt = 0; dt < 2; dt++)
#pragma unroll
      for (int r = 0; r < 4; r++)
        lo[col * 34 + dt * 16 + quad * 4 + r] = oacc[dt][r];
  }
  __syncthreads();
  if (wave == 0) {
    int t = (q0 + col) * BATCH + b;
#pragma unroll
    for (int dt = 0; dt < 2; dt++) {
      f32x4 vv = {};
#pragma unroll
      for (int w = 0; w < 4; w++) {
        const float* lw = &lds_pn[w][0][0];
#pragma unroll
        for (int r2 = 0; r2 < 4; r2++)
          vv[r2] += lw[col * 34 + dt * 16 + quad * 4 + r2];
      }
      *(f32x4*)(attn_out + (size_t)t * DMODEL + h * DKH + dt * 16 + quad * 4) = vv;
    }
  }
}

// ---------------- kernel 4: FC + residual + LayerNorm -----------------------
__global__ __launch_bounds__(256) void k_fc_ln(
    const float* __restrict__ attn_out, const bf16_t* __restrict__ wtfc,
    const bf16_t* __restrict__ qc, const void* __restrict__ gamma,
    const void* __restrict__ beta, void* __restrict__ out0,
    const int* __restrict__ flag) {
  __shared__ float lds_sx[4][16];
  __shared__ float lds_sq[4][16];
  int is32 = *flag;
  int t0 = blockIdx.x * 16;
  int lane = threadIdx.x & 63, wave = threadIdx.x >> 6;
  int col = lane & 15, quad = lane >> 4;
  f32x4 acc[4] = {};
  const float* arow = attn_out + (size_t)(t0 + col) * DMODEL + quad * 8;
  for (int kk = 0; kk < 8; kk++) {
    float4 a0 = *(const float4*)(arow + kk * 32);
    float4 a1 = *(const float4*)(arow + kk * 32 + 4);
    float av[8] = {a0.x, a0.y, a0.z, a0.w, a1.x, a1.y, a1.z, a1.w};
    bf16x8 ahi, alo;
#pragma unroll
    for (int j = 0; j < 8; j++) {
      bf16_t hi = (bf16_t)av[j];
      ahi[j] = hi;
      alo[j] = (bf16_t)(av[j] - (float)hi);
    }
#pragma unroll
    for (int nt = 0; nt < 4; nt++) {
      int n0 = wave * 64 + nt * 16;
      bf16x8 bfr = *(const bf16x8*)(wtfc + (size_t)(n0 + col) * DMODEL + kk * 32 + quad * 8);
      acc[nt] = MFMA16(ahi, bfr, acc[nt]);
      acc[nt] = MFMA16(alo, bfr, acc[nt]);
    }
  }
#pragma unroll
  for (int nt = 0; nt < 4; nt++) {
    int n = wave * 64 + nt * 16 + col;
#pragma unroll
    for (int r = 0; r < 4; r++) {
      int t = t0 + quad * 4 + r;
      acc[nt][r] += (float)qc[(size_t)t * DMODEL + n];
    }
  }
  float sx[4], sq[4];
#pragma unroll
  for (int r = 0; r < 4; r++) {
    float s = 0, s2 = 0;
#pragma unroll
    for (int nt = 0; nt < 4; nt++) { float v = acc[nt][r]; s += v; s2 += v * v; }
    sx[r] = s; sq[r] = s2;
  }
#pragma unroll
  for (int off = 1; off < 16; off <<= 1) {
#pragma unroll
    for (int r = 0; r < 4; r++) {
      sx[r] += __shfl_xor(sx[r], off);
      sq[r] += __shfl_xor(sq[r], off);
    }
  }
  if (col == 0) {
#pragma unroll
    for (int r = 0; r < 4; r++) {
      lds_sx[wave][quad * 4 + r] = sx[r];
      lds_sq[wave][quad * 4 + r] = sq[r];
    }
  }
  __syncthreads();
#pragma unroll
  for (int r = 0; r < 4; r++) {
    int tl = quad * 4 + r;
    float tsx = lds_sx[0][tl] + lds_sx[1][tl] + lds_sx[2][tl] + lds_sx[3][tl];
    float tsq = lds_sq[0][tl] + lds_sq[1][tl] + lds_sq[2][tl] + lds_sq[3][tl];
    float mu = tsx * (1.0f / 256.0f);
    float var = tsq * (1.0f / 256.0f) - mu * mu;
    float rs = rsqrtf(var + 1e-6f);
    int t = t0 + tl;
#pragma unroll
    for (int nt = 0; nt < 4; nt++) {
      int n = wave * 64 + nt * 16 + col;
      float g = is32 ? ((const float*)gamma)[n] : (float)((const bf16_t*)gamma)[n];
      float bt = is32 ? ((const float*)beta)[n] : (float)((const bf16_t*)beta)[n];
      float val = (acc[nt][r] - mu) * rs * g + bt;
      if (is32) ((float*)out0)[(size_t)t * DMODEL + n] = val;
      else      ((bf16_t*)out0)[(size_t)t * DMODEL + n] = (bf16_t)val;
    }
  }
}

extern "C" void kernel_launch(void* const* d_in, const int* in_sizes, int n_in,
                              void* d_out, int out_size, void* d_ws, size_t ws_size,
                              hipStream_t stream) {
  (void)in_sizes; (void)n_in; (void)out_size;
  const void* qin   = d_in[0];
  const void* kin   = d_in[1];
  const void* vin   = d_in[2];
  const void* gp    = d_in[3];
  const int*  mask  = (const int*)d_in[4];
  const void* w_q   = d_in[5];
  const void* w_k   = d_in[6];
  const void* w_v   = d_in[7];
  const void* w_fc  = d_in[8];
  const void* gamma = d_in[9];
  const void* beta  = d_in[10];

  char* ws = (char*)d_ws;
  bf16_t* wt  = (bf16_t*)(ws);                  // 512 KB
  int* flag = (int*)(ws + (1u << 19));          // 4 B (after wt)
  bf16_t* qc  = (bf16_t*)(ws + (1u << 20));     // 2 MB
  bf16_t* kc  = (bf16_t*)(ws + (3u << 20));     // 2 MB
  bf16_t* vc  = (bf16_t*)(ws + (5u << 20));     // 2 MB
  bf16_t* qhi = (bf16_t*)(ws + (7u << 20));
  bf16_t* qlo = (bf16_t*)(ws + (9u << 20));
  bf16_t* khi = (bf16_t*)(ws + (11u << 20));
  bf16_t* klo = (bf16_t*)(ws + (13u << 20));
  bf16_t* vt  = (bf16_t*)(ws + (15u << 20));
  float* attn_out = (float*)(ws + (17u << 20)); // 4 MB
  unsigned int* mbits = (unsigned int*)(ws + (21u << 20));  // 1 MB
  bf16_t* gpt = (bf16_t*)(ws + (22u << 20));    // 64 MB when available

  bool use_ws_gpt = ws_size >= (((size_t)86 << 20) + 64);

  hipLaunchKernelGGL(k_probe, dim3(1), dim3(64), 0, stream,
                     (const unsigned short*)qin, flag);
  hipLaunchKernelGGL(k_prep, dim3(16640), dim3(256), 0, stream,
                     qin, kin, vin, qc, kc, vc, w_q, w_k, w_v, w_fc, wt,
                     gp, gpt, d_out, mask, mbits, flag, use_ws_gpt ? 0 : 1);
  hipLaunchKernelGGL(k_proj, dim3(256, 1, 3), dim3(256), 0, stream,
                     qc, kc, vc, wt, qhi, qlo, khi, klo, vt);
  if (use_ws_gpt) {
    hipLaunchKernelGGL((k_attn<0>), dim3(128, 8, 2), dim3(256), 0, stream,
                       qhi, qlo, khi, klo, vt, gpt, mbits, d_out, attn_out, flag);
  } else {
    hipLaunchKernelGGL((k_attn<1>), dim3(128, 8, 2), dim3(256), 0, stream,
                       qhi, qlo, khi, klo, vt, gpt, mbits, d_out, attn_out, flag);
  }
  hipLaunchKernelGGL(k_fc_ln, dim3(256), dim3(256), 0, stream,
                     attn_out, wt + 3 * DMODEL * DMODEL, qc, gamma, beta, d_out, flag);
}